// Round 2
// baseline (357.452 us; speedup 1.0000x reference)
//
#include <hip/hip_runtime.h>

#define NUM_MLP 8
#define HD 16

constexpr int BLK = 128;   // 2 waves per block
constexpr int P   = 4;     // points per thread

// ---------- activations (fast fp32, native transcendentals) ----------
__device__ __forceinline__ float fast_rcp(float x) { return __builtin_amdgcn_rcpf(x); }

__device__ __forceinline__ float fast_tanh(float x) {
    float e = __expf(-2.0f * fabsf(x));
    float t = 1.0f - 2.0f * e * fast_rcp(1.0f + e);
    return copysignf(t, x);
}

template<int A> __device__ __forceinline__ float act_fn(float x);
// 0: relu
template<> __device__ __forceinline__ float act_fn<0>(float x) { return fmaxf(x, 0.0f); }
// 1: tanh
template<> __device__ __forceinline__ float act_fn<1>(float x) { return fast_tanh(x); }
// 2: elu (alpha=1)
template<> __device__ __forceinline__ float act_fn<2>(float x) {
    return x > 0.0f ? x : (__expf(x) - 1.0f);
}
// 3: silu = x * sigmoid(x)
template<> __device__ __forceinline__ float act_fn<3>(float x) {
    return x * fast_rcp(1.0f + __expf(-x));
}
// 4: gelu — tanh approximation (max |err| vs exact ~3e-3, x 1/12 weight -> negligible)
template<> __device__ __forceinline__ float act_fn<4>(float x) {
    float u = 0.7978845608028654f * fmaf(0.044715f * x, x * x, x);
    return 0.5f * x * (1.0f + fast_tanh(u));
}
// 5: identity
template<> __device__ __forceinline__ float act_fn<5>(float x) { return x; }
// 6: selu
template<> __device__ __forceinline__ float act_fn<6>(float x) {
    const float sc = 1.0507009873554805f;
    const float al = 1.6732632423543772f;
    return x > 0.0f ? sc * x : (sc * al) * (__expf(x) - 1.0f);
}
// 7: softplus = max(x,0) + log1p(exp(-|x|))
template<> __device__ __forceinline__ float act_fn<7>(float x) {
    return fmaxf(x, 0.0f) + __logf(1.0f + __expf(-fabsf(x)));
}

// ---------- one expert's 16 hidden units over P points ----------
template<int A>
__device__ __forceinline__ void run_expert(const float4* __restrict__ wpack,
                                           const float*  __restrict__ w2pack,
                                           const float* re, const float* im,
                                           const float* am, float* acc) {
#pragma unroll
    for (int h = 0; h < HD; ++h) {
        float4 w  = wpack[A * HD + h];   // {w1_re, w1_im, w1_amp, b1}
        float  w2 = w2pack[A * HD + h];  // ew[i] * W2[i][h]
#pragma unroll
        for (int k = 0; k < P; ++k) {
            float z = fmaf(re[k], w.x, fmaf(im[k], w.y, fmaf(am[k], w.z, w.w)));
            acc[k] = fmaf(act_fn<A>(z), w2, acc[k]);
        }
    }
}

__global__ __launch_bounds__(BLK, 4)   // cap VGPR at 128 -> 4 waves/SIMD
void moe_kernel(const float* __restrict__ x,
                const float* __restrict__ W1,
                const float* __restrict__ b1,
                const float* __restrict__ W2,
                const float* __restrict__ b2,
                const float* __restrict__ ew,
                float* __restrict__ out, int npts) {
    __shared__ float4 wpack[NUM_MLP * HD];
    __shared__ float  w2pack[NUM_MLP * HD];

    const int tid = threadIdx.x;
    if (tid < NUM_MLP * HD) {
        int i = tid >> 4;   // expert
        int h = tid & 15;   // hidden unit
        // W1: (8,3,16) flat i*48 + r*16 + h ; b1: (8,16) ; W2: (8,16,1)
        wpack[tid]  = make_float4(W1[i * 48 + h],
                                  W1[i * 48 + 16 + h],
                                  W1[i * 48 + 32 + h],
                                  b1[tid]);
        w2pack[tid] = W2[tid] * ew[i];
    }

    float bconst = 0.0f;
#pragma unroll
    for (int i = 0; i < NUM_MLP; ++i) bconst += ew[i] * b2[i];
    const float ewA = ew[8], ewM = ew[9], ewS = ew[10], ewC = ew[11];

    __syncthreads();

    const int base = blockIdx.x * (BLK * P) + tid;
    float re[P], im[P], am[P], acc[P];

#pragma unroll
    for (int k = 0; k < P; ++k) {
        int p = base + k * BLK;
        float2 v = (p < npts) ? reinterpret_cast<const float2*>(x)[p]
                              : make_float2(0.0f, 0.0f);
        re[k] = v.x;
        im[k] = v.y;
        am[k] = __builtin_amdgcn_sqrtf(fmaf(v.x, v.x, v.y * v.y));
        float a = fmaf(ewA, fabsf(v.x) + fabsf(v.y), bconst);  // 'abs' + folded b2
        a = fmaf(ewM, am[k], a);                               // 'modulus'
        a = fmaf(ewS, __sinf(am[k]), a);                       // 'sin'
        a = fmaf(ewC, __cosf(am[k]), a);                       // 'cos'
        acc[k] = a;
    }

    run_expert<0>(wpack, w2pack, re, im, am, acc);  // relu
    run_expert<1>(wpack, w2pack, re, im, am, acc);  // tanh
    run_expert<2>(wpack, w2pack, re, im, am, acc);  // elu
    run_expert<3>(wpack, w2pack, re, im, am, acc);  // silu
    run_expert<4>(wpack, w2pack, re, im, am, acc);  // gelu (tanh approx)
    run_expert<5>(wpack, w2pack, re, im, am, acc);  // none
    run_expert<6>(wpack, w2pack, re, im, am, acc);  // selu
    run_expert<7>(wpack, w2pack, re, im, am, acc);  // softplus

#pragma unroll
    for (int k = 0; k < P; ++k) {
        int p = base + k * BLK;
        if (p < npts) out[p] = acc[k];
    }
}

extern "C" void kernel_launch(void* const* d_in, const int* in_sizes, int n_in,
                              void* d_out, int out_size, void* d_ws, size_t ws_size,
                              hipStream_t stream) {
    const float* x  = (const float*)d_in[0];
    const float* W1 = (const float*)d_in[1];
    const float* b1 = (const float*)d_in[2];
    const float* W2 = (const float*)d_in[3];
    const float* b2 = (const float*)d_in[4];
    const float* ew = (const float*)d_in[5];
    float* out = (float*)d_out;

    const int npts = in_sizes[0] / 2;  // (B,S,C,2) -> B*S*C points
    const int blocks = (npts + BLK * P - 1) / (BLK * P);
    hipLaunchKernelGGL(moe_kernel, dim3(blocks), dim3(BLK), 0, stream,
                       x, W1, b1, W2, b2, ew, out, npts);
}

// Round 3
// 29.662 us; speedup vs baseline: 12.0509x; 12.0509x over previous
//
#include <hip/hip_runtime.h>

#define NUM_MLP 8
#define HD 16

constexpr int BLK = 256;
constexpr int P   = 2;     // adjacent points per thread

// ---------- activations (fast fp32, native transcendentals) ----------
__device__ __forceinline__ float fast_rcp(float x) { return __builtin_amdgcn_rcpf(x); }

__device__ __forceinline__ float fast_tanh(float x) {
    float e = __expf(-2.0f * fabsf(x));
    float t = 1.0f - 2.0f * e * fast_rcp(1.0f + e);
    return copysignf(t, x);
}

template<int A> __device__ __forceinline__ float act_fn(float x);
template<> __device__ __forceinline__ float act_fn<0>(float x) { return fmaxf(x, 0.0f); }          // relu
template<> __device__ __forceinline__ float act_fn<1>(float x) { return fast_tanh(x); }            // tanh
template<> __device__ __forceinline__ float act_fn<2>(float x) {                                   // elu
    return x > 0.0f ? x : (__expf(x) - 1.0f);
}
template<> __device__ __forceinline__ float act_fn<3>(float x) {                                   // silu
    return x * fast_rcp(1.0f + __expf(-x));
}
template<> __device__ __forceinline__ float act_fn<4>(float x) {                                   // gelu (tanh approx)
    float u = 0.7978845608028654f * fmaf(0.044715f * x, x * x, x);
    return 0.5f * x * (1.0f + fast_tanh(u));
}
template<> __device__ __forceinline__ float act_fn<5>(float x) { return x; }                       // none
template<> __device__ __forceinline__ float act_fn<6>(float x) {                                   // selu
    const float sc = 1.0507009873554805f;
    const float al = 1.6732632423543772f;
    return x > 0.0f ? sc * x : (sc * al) * (__expf(x) - 1.0f);
}
template<> __device__ __forceinline__ float act_fn<7>(float x) {                                   // softplus
    return fmaxf(x, 0.0f) + __logf(1.0f + __expf(-fabsf(x)));
}

// ---------- one expert: weights via uniform (scalar) loads ----------
template<int A>
__device__ __forceinline__ void run_expert(const float* __restrict__ W1,
                                           const float* __restrict__ b1,
                                           const float* __restrict__ W2,
                                           const float* __restrict__ ew,
                                           const float* re, const float* im,
                                           const float* am, float* acc) {
    float accE[P];
#pragma unroll
    for (int k = 0; k < P; ++k) accE[k] = 0.0f;

#pragma unroll 1   // runtime loop: bounds the scheduler's load-hoisting window
    for (int hb = 0; hb < HD / 4; ++hb) {
#pragma unroll
        for (int hh = 0; hh < 4; ++hh) {
            const int h = hb * 4 + hh;
            // all indices thread-uniform -> s_load (scalar cache, no VGPRs)
            const float wre = W1[A * 48 + h];
            const float wim = W1[A * 48 + 16 + h];
            const float wam = W1[A * 48 + 32 + h];
            const float bb  = b1[A * 16 + h];
            const float w2  = W2[A * 16 + h];
#pragma unroll
            for (int k = 0; k < P; ++k) {
                float z = fmaf(re[k], wre, fmaf(im[k], wim, fmaf(am[k], wam, bb)));
                accE[k] = fmaf(act_fn<A>(z), w2, accE[k]);
            }
        }
    }
    const float ewI = ew[A];
#pragma unroll
    for (int k = 0; k < P; ++k) acc[k] = fmaf(accE[k], ewI, acc[k]);
    __builtin_amdgcn_sched_barrier(0);   // no cross-expert code motion
}

__global__ __launch_bounds__(BLK)
void moe_kernel(const float* __restrict__ x,
                const float* __restrict__ W1,
                const float* __restrict__ b1,
                const float* __restrict__ W2,
                const float* __restrict__ b2,
                const float* __restrict__ ew,
                float* __restrict__ out, int npts) {
    const int p0 = blockIdx.x * (BLK * P) + threadIdx.x * P;
    if (p0 >= npts) return;

    float bconst = 0.0f;
#pragma unroll
    for (int i = 0; i < NUM_MLP; ++i) bconst = fmaf(ew[i], b2[i], bconst);
    const float ewA = ew[8], ewM = ew[9], ewS = ew[10], ewC = ew[11];

    // two adjacent points: one float4 load (16B/lane, coalesced)
    float4 v = reinterpret_cast<const float4*>(x)[p0 >> 1];
    float re[P] = {v.x, v.z};
    float im[P] = {v.y, v.w};
    float am[P], acc[P];

#pragma unroll
    for (int k = 0; k < P; ++k) {
        am[k] = __builtin_amdgcn_sqrtf(fmaf(re[k], re[k], im[k] * im[k]));
        float a = fmaf(ewA, fabsf(re[k]) + fabsf(im[k]), bconst);  // 'abs' + folded b2
        a = fmaf(ewM, am[k], a);                                   // 'modulus'
        a = fmaf(ewS, __sinf(am[k]), a);                           // 'sin'
        a = fmaf(ewC, __cosf(am[k]), a);                           // 'cos'
        acc[k] = a;
    }

    run_expert<0>(W1, b1, W2, ew, re, im, am, acc);  // relu
    run_expert<1>(W1, b1, W2, ew, re, im, am, acc);  // tanh
    run_expert<2>(W1, b1, W2, ew, re, im, am, acc);  // elu
    run_expert<3>(W1, b1, W2, ew, re, im, am, acc);  // silu
    run_expert<4>(W1, b1, W2, ew, re, im, am, acc);  // gelu
    run_expert<5>(W1, b1, W2, ew, re, im, am, acc);  // none
    run_expert<6>(W1, b1, W2, ew, re, im, am, acc);  // selu
    run_expert<7>(W1, b1, W2, ew, re, im, am, acc);  // softplus

    reinterpret_cast<float2*>(out)[p0 >> 1] = make_float2(acc[0], acc[1]);
}

extern "C" void kernel_launch(void* const* d_in, const int* in_sizes, int n_in,
                              void* d_out, int out_size, void* d_ws, size_t ws_size,
                              hipStream_t stream) {
    const float* x  = (const float*)d_in[0];
    const float* W1 = (const float*)d_in[1];
    const float* b1 = (const float*)d_in[2];
    const float* W2 = (const float*)d_in[3];
    const float* b2 = (const float*)d_in[4];
    const float* ew = (const float*)d_in[5];
    float* out = (float*)d_out;

    const int npts = in_sizes[0] / 2;  // (B,S,C,2) -> B*S*C points
    const int blocks = (npts + BLK * P - 1) / (BLK * P);
    hipLaunchKernelGGL(moe_kernel, dim3(blocks), dim3(BLK), 0, stream,
                       x, W1, b1, W2, b2, ew, out, npts);
}